// Round 3
// baseline (145.200 us; speedup 1.0000x reference)
//
#include <hip/hip_runtime.h>

// HQQ 4-bit dequant + linear (Llama-7B up-proj, decode: 8 tokens)
// OUT=11008, IN=4096, GS=64, G=704512, OC=172 (=G/IN; OUT=64*OC)
// W_q: [32, G] int32 (one byte per word: hi nibble -> unpacked row rq,
//      lo nibble -> row rq+32 of the [64, G] tensor)
// Mapping: W_r[o, i] with r=o/172, oc=o%172, g=oc*4096+i.
//
// R6 theory: R5's __syncthreads() drains vmcnt(0) -> the 8 Wq loads (the
// cold 90 MB stream) always complete BEFORE compute, so blocks alternate
// {issue burst | dead wait | compute with 0 bytes in flight} in lockstep.
// Fix: counted-wait barrier (T4). Issue 10 LDS-DMA ops, fence, 8 Wq loads,
// then "s_waitcnt vmcnt(8); s_barrier". vmcnt is FIFO -> the 10 oldest
// (all DMA, needed for cross-wave LDS reads) are retired; Wq stays in
// flight across the barrier and drains via the compiler's precise
// per-register counted waits inside the compute loop.
// Also: reduce kernel re-indexed so ws reads are coalesced (scatter moved
// to the store side).

#define OUT_ 11008
#define IN_ 4096
#define G_ 704512
#define OC_ 172
#define KS 4
#define KC (IN_ / KS)      // 1024
#define ITERS (KC / 256)   // 4
#define SIB (OC_ * KS)     // 688; 688%8==0 so bx-siblings land on same XCD
#define NB (4 * SIB)       // 2752 blocks

typedef const __attribute__((address_space(1))) void* gptr1_t;
typedef __attribute__((address_space(3))) void* sptr3_t;

__device__ __forceinline__ void gload_lds16(const float* g, float* l) {
    // dest is wave-uniform; HW adds lane*16B. src is per-lane.
    __builtin_amdgcn_global_load_lds((gptr1_t)g, (sptr3_t)l, 16, 0, 0);
}

__global__ __launch_bounds__(256, 4)
void hqq_gemv(const int* __restrict__ Wq, const float* __restrict__ scale,
              const float* __restrict__ zero, const float* __restrict__ x,
              float* __restrict__ ws) {
    __shared__ float x_lds[8 * KC];   // 32 KB; reused as red[128*64] at tail
    __shared__ float s_lds[KC];       // 4 KB
    __shared__ float z_lds[KC];       // 4 KB

    const int lane = threadIdx.x;              // 0..63
    const int ty   = threadIdx.y;              // 0..3
    const int tid  = ty * 64 + lane;
    const int bid  = blockIdx.x;
    const int bx   = bid / SIB;                // 0..3  (rq-group of 8 rows)
    const int rem  = bid % SIB;
    const int oc   = rem >> 2;                 // 0..171
    const int ks   = rem & 3;                  // 0..3
    const int rq0  = bx * 8 + ty * 2;          // packed rows rq0, rq0+1

    const int kbase = ks * KC;
    const int gb = oc * IN_ + kbase;

    // ---- phase 1: issue the 10 LDS-DMA ops (s, z, 8x x) ----
    const int wf = ty * 256;                   // wave's float offset per round
    gload_lds16(scale + gb + wf + lane * 4, s_lds + wf);
    gload_lds16(zero  + gb + wf + lane * 4, z_lds + wf);
#pragma unroll
    for (int r = 0; r < 8; ++r) {              // round r covers batch b=r
        gload_lds16(x + r * IN_ + kbase + wf + lane * 4, x_lds + r * 1024 + wf);
    }

    // compiler fence: keep all DMA issues strictly before the Wq loads so
    // the vmcnt(8) below covers exactly the 10 DMA ops (FIFO).
    asm volatile("" ::: "memory");

    // ---- phase 2: issue ALL Wq loads for this wave (8 dwordx4, 32 VGPR) ----
    const int* __restrict__ wqA = Wq + (long)rq0 * G_ + gb;
    const int* __restrict__ wqB = wqA + G_;
    int4 qA[ITERS], qB[ITERS];
#pragma unroll
    for (int it = 0; it < ITERS; ++it) {
        qA[it] = *(const int4*)(wqA + it * 256 + lane * 4);
        qB[it] = *(const int4*)(wqB + it * 256 + lane * 4);
    }

    // ---- counted-wait barrier: drain own DMA (10 oldest), keep Wq in
    // flight across the barrier. Every wave does this -> cross-wave LDS
    // reads are safe. Compute's qA/qB uses get compiler-counted waits.
    asm volatile("s_waitcnt vmcnt(8)\n\ts_barrier" ::: "memory");

    // acc[0]=hi(rq0) acc[1]=lo(rq0) acc[2]=hi(rq0+1) acc[3]=lo(rq0+1)
    float acc[4][8];
#pragma unroll
    for (int r = 0; r < 4; ++r)
#pragma unroll
        for (int b = 0; b < 8; ++b) acc[r][b] = 0.f;

#pragma unroll
    for (int it = 0; it < ITERS; ++it) {
        const int i = it * 256 + lane * 4;
        const float4 s4 = *(const float4*)(s_lds + i);
        const float4 z4 = *(const float4*)(z_lds + i);
        const float ss[4] = {s4.x, s4.y, s4.z, s4.w};
        const float zs[4] = {-z4.x * s4.x, -z4.y * s4.y, -z4.z * s4.z, -z4.w * s4.w};
        const int qsA[4] = {qA[it].x, qA[it].y, qA[it].z, qA[it].w};
        const int qsB[4] = {qB[it].x, qB[it].y, qB[it].z, qB[it].w};

        float w[4][4];  // [hiA, loA, hiB, loB][j]
#pragma unroll
        for (int j = 0; j < 4; ++j) {
            w[0][j] = fmaf((float)((qsA[j] >> 4) & 0xF), ss[j], zs[j]);
            w[1][j] = fmaf((float)( qsA[j]       & 0xF), ss[j], zs[j]);
            w[2][j] = fmaf((float)((qsB[j] >> 4) & 0xF), ss[j], zs[j]);
            w[3][j] = fmaf((float)( qsB[j]       & 0xF), ss[j], zs[j]);
        }
#pragma unroll
        for (int b = 0; b < 8; ++b) {
            const float4 xb = *(const float4*)(x_lds + b * KC + i);
#pragma unroll
            for (int r = 0; r < 4; ++r) {
                float a = acc[r][b];
                a = fmaf(xb.x, w[r][0], a);
                a = fmaf(xb.y, w[r][1], a);
                a = fmaf(xb.z, w[r][2], a);
                a = fmaf(xb.w, w[r][3], a);
                acc[r][b] = a;
            }
        }
    }

    // ---- LDS transpose reduce over the 64 K-slice lanes ----
    // red row o holds acc values from all 64 lanes; write side is a lane
    // permutation (free); read side: slot = (j ^ (o&7)) -> all 8 slots.
    float* red = x_lds;                        // x no longer needed
    __syncthreads();
    const int obase = ty * 32;
#pragma unroll
    for (int r = 0; r < 4; ++r)
#pragma unroll
        for (int b = 0; b < 8; ++b) {
            const int o = obase + r * 8 + b;
            red[o * 64 + (lane ^ ((o & 7) << 2))] = acc[r][b];
        }
    __syncthreads();

    if (tid < 128) {
        const int o = tid;                     // o = w_*32 + r*8 + b
        const int c = (o & 7) << 2;
        float s = 0.f;
#pragma unroll
        for (int j = 0; j < 16; ++j) {
            const float4 v = *(const float4*)(red + o * 64 + ((j * 4) ^ c));
            s += (v.x + v.y) + (v.z + v.w);
        }
        // coalesced: this block's 128 partials are contiguous
        ws[(long)((bx * OC_ + oc) * KS + ks) * 128 + o] = s;
    }
}

__global__ void hqq_reduce(const float* __restrict__ ws,
                           const float* __restrict__ bias,
                           float* __restrict__ out) {
    // thread t = ws slot (c, o): reads coalesced, scatter on the store side.
    const int t = blockIdx.x * 256 + threadIdx.x;  // 0 .. 688*128-1 = 88063
    if (t >= (NB / KS) * 128) return;
    const int c = t >> 7;                      // chunk = bx*OC_ + oc, 0..687
    const int o = t & 127;                     // o = w_*32 + r*8 + b
    float v = 0.f;
#pragma unroll
    for (int k = 0; k < KS; ++k) v += ws[(c << 9) + (k << 7) + o];
    const int bx = c / OC_;
    const int oc = c % OC_;
    const int w_ = o >> 5;
    const int r  = (o >> 3) & 3;
    const int b  = o & 7;
    const int rq  = bx * 8 + w_ * 2 + (r >> 1);
    const int row = rq + ((r & 1) ? 32 : 0);
    const int oo  = row * OC_ + oc;
    out[b * OUT_ + oo] = v + bias[oo];
}

extern "C" void kernel_launch(void* const* d_in, const int* in_sizes, int n_in,
                              void* d_out, int out_size, void* d_ws, size_t ws_size,
                              hipStream_t stream) {
    const int*   Wq    = (const int*)d_in[0];    // [32, 704512] int32
    const float* scale = (const float*)d_in[1];  // [1, 704512]
    const float* zero  = (const float*)d_in[2];  // [1, 704512]
    const float* x     = (const float*)d_in[3];  // [8, 1, 4096]
    const float* bias  = (const float*)d_in[4];  // [11008]
    float* out = (float*)d_out;                  // [8, 1, 11008]
    float* ws  = (float*)d_ws;                   // NB*128 floats = 1.38 MB

    dim3 grid(NB);          // 2752, XCD-aligned sibling groups
    dim3 block(64, 4);
    hqq_gemv<<<grid, block, 0, stream>>>(Wq, scale, zero, x, ws);
    hqq_reduce<<<((NB / KS) * 128 + 255) / 256, 256, 0, stream>>>(ws, bias, out);
}